// Round 9
// baseline (167.527 us; speedup 1.0000x reference)
//
#include <hip/hip_runtime.h>

#define NTH 512   // 8 waves; 16 rows/block; grid 512 -> 2 blocks/CU = 16 waves/CU

typedef _Float16 half8 __attribute__((ext_vector_type(8)));
typedef _Float16 half4 __attribute__((ext_vector_type(4)));
typedef __attribute__((ext_vector_type(4))) float floatx4;

#define LOG2E 1.44269504088896340736f

// DPP add stage; 0x140,0x141,0x4E,0xB1 together = 16-lane sum broadcast
template<int CTRL>
__device__ __forceinline__ float dpp_add(float v) {
    int o = __builtin_amdgcn_update_dpp(0, __float_as_int(v), CTRL, 0xF, 0xF, true);
    return v + __int_as_float(o);
}

#define MFMA16 __builtin_amdgcn_mfma_f32_16x16x32_f16

// MFMA with B operand pinned to AGPRs ("a" constraint): keeps the 64 regs of
// persistent weights out of the arch-VGPR file. hipcc never does this on its
// own (R1/R6/R7 all spilled at the 128-reg budget); gfx950 MFMA reads A/B
// from AGPR directly, so this is free at issue time.
__device__ __forceinline__ void mfma_ag(floatx4& c, half8 a, const half8& b) {
    asm("v_mfma_f32_16x16x32_f16 %0, %1, %2, %0"
        : "+v"(c) : "v"(a), "a"(b));
}

// ---------------------------------------------------------------------------
// Encoder layer core (MFMA): acc = bias + src[16,K] @ W[K,128] on col
// jc = w*16 + l15 (8 waves cover 128 cols). src is f16 LDS, rows of ROWH
// halves, 8-elem chunks rotation-swizzled by row with mask CMASK.
// ---------------------------------------------------------------------------
template<int KTILES, int CMASK, int ROWH>
__device__ __forceinline__ void enc_layer(const _Float16* __restrict__ src,
                                          const float* __restrict__ W,
                                          const float* __restrict__ bias,
                                          int jc, int quad, int l15,
                                          floatx4& acc) {
    const float bv = bias[jc];
    acc = (floatx4){bv, bv, bv, bv};
    #pragma unroll
    for (int kt = 0; kt < KTILES; kt++) {
        const int kb = kt * 32 + quad * 8;
        half8 hv;
        #pragma unroll
        for (int e = 0; e < 8; e++) hv[e] = (_Float16)W[(kb + e) * 128 + jc];
        const half8 av = *(const half8*)(src + l15 * ROWH +
                                         (((kt * 4 + quad) + l15) & CMASK) * 8);
        acc = MFMA16(av, hv, acc, 0, 0, 0);
    }
}

// store MFMA C (row=quad*4+reg, col=jc) into f16 [16][128] with &15 swizzle
__device__ __forceinline__ void enc_store(_Float16* __restrict__ dst,
                                          const floatx4& acc,
                                          int jc, int quad, int l15, bool relu) {
    #pragma unroll
    for (int reg = 0; reg < 4; reg++) {
        const int row = quad * 4 + reg;
        float v = acc[reg];
        if (relu) v = fmaxf(v, 0.f);
        dst[row * 128 + ((((jc >> 3) + row) & 15) << 3) + (jc & 7)] = (_Float16)v;
    }
}

// ---------------------------------------------------------------------------
// Fully-MFMA encoder + 50-iter GRU + decoder. 16 rows/block, EIGHT waves;
// wave w owns gate col slice jc = w*16 + l15. Grid 512 -> 2 blocks/CU =
// 16 waves/CU = 4 independent streams/SIMD (vs 2 for the 4-wave shape that
// plateaued at 86-88us with VALUBusy ~48% = 1-(1-d)^2, d~0.28).
// Register plan at the 128-reg/wave unified budget (launch_bounds(512,4)):
//   AGPR a[0:63]: wb16[3][4] (48) + dw16[4] (16) via "a"-constrained asm MFMA
//   VGPR ~60: acc 16 + ahk 8 (per-kt) + hold 4 + consts 10 + offsets 8 + temps
// Falsifier: WRITE_SIZE must stay ~1.6MB (no spill).
// Gate math: exp2-prescale + merged z/n single-rcp update; per-thread gate
// work halved vs 4-wave shape (4 elems).
// ---------------------------------------------------------------------------
__global__ __launch_bounds__(NTH, 4)
void gru_fused_kernel(const float* __restrict__ x,
                      const float* __restrict__ ew0, const float* __restrict__ eb0,
                      const float* __restrict__ ew1, const float* __restrict__ eb1,
                      const float* __restrict__ ew2, const float* __restrict__ eb2,
                      const float* __restrict__ w_ih, const float* __restrict__ w_hh,
                      const float* __restrict__ b_ih, const float* __restrict__ b_hh,
                      const float* __restrict__ dw0, const float* __restrict__ db0,
                      const float* __restrict__ dw1, const float* __restrict__ db1,
                      float* __restrict__ out) {
    __shared__ __align__(16) _Float16 encx[16 * 256];   // x stage (8KB); reused as h2
    __shared__ __align__(16) _Float16 h1b[16 * 128];    // layer-1 out (4KB)
    __shared__ __align__(16) _Float16 h16[2 * 16 * 128];// h planes dbuf (8KB)
    __shared__ float outb[16][52];

    const int tid  = threadIdx.x;
    const int b0   = blockIdx.x * 16;
    const int lane = tid & 63;
    const int w    = tid >> 6;     // wave 0..7
    const int quad = lane >> 4;
    const int l15  = lane & 15;
    const int jc   = w * 16 + l15; // this wave's gate/h column

    // ---------------- stage x -> f16 LDS (chunk-rotation swizzle &31) ------
    #pragma unroll
    for (int i = 0; i < 2; i++) {
        const int e = tid + i * NTH;          // 0..1023 float4s
        const int row = e >> 6, c4 = e & 63;
        const float4 xv = *(const float4*)(x + (size_t)(b0 + row) * 256 + c4 * 4);
        half4 hv = {(_Float16)xv.x, (_Float16)xv.y, (_Float16)xv.z, (_Float16)xv.w};
        *(half4*)(encx + row * 256 + (((c4 >> 1) + row) & 31) * 8 + (c4 & 1) * 4) = hv;
    }
    __syncthreads();

    // ---------------- encoder: 3 MFMA layers ----------------
    floatx4 ea;
    enc_layer<8, 31, 256>(encx, ew0, eb0, jc, quad, l15, ea);
    enc_store(h1b, ea, jc, quad, l15, true);
    __syncthreads();
    enc_layer<4, 15, 128>(h1b, ew1, eb1, jc, quad, l15, ea);
    enc_store(encx, ea, jc, quad, l15, true);      // h2 reuses encx (stride 128)
    __syncthreads();
    enc_layer<4, 15, 128>(encx, ew2, eb2, jc, quad, l15, ea);
    // h_0: lane-private fp32 copy + publish f16 plane 0
    float hold[4];
    #pragma unroll
    for (int reg = 0; reg < 4; reg++) hold[reg] = ea[reg];
    enc_store(h16, ea, jc, quad, l15, false);
    if (tid < 16) outb[tid][0] = 0.f;

    // ---------------- persistent weights -> AGPRs (f16, exp2-prescaled) ----
    half8 wb16[3][4];
    #pragma unroll
    for (int g = 0; g < 3; g++) {
        const float scale = (g == 2) ? 2.f * LOG2E : LOG2E;
        const float* wrow = w_hh + (g * 128 + jc) * 128;
        #pragma unroll
        for (int kt = 0; kt < 4; kt++) {
            const int kb = kt * 32 + quad * 8;
            const float4 w0 = *(const float4*)(wrow + kb);
            const float4 w1 = *(const float4*)(wrow + kb + 4);
            half8 hv;
            hv[0] = (_Float16)(w0.x * scale); hv[1] = (_Float16)(w0.y * scale);
            hv[2] = (_Float16)(w0.z * scale); hv[3] = (_Float16)(w0.w * scale);
            hv[4] = (_Float16)(w1.x * scale); hv[5] = (_Float16)(w1.y * scale);
            hv[6] = (_Float16)(w1.z * scale); hv[7] = (_Float16)(w1.w * scale);
            wb16[g][kt] = hv;
        }
    }
    half8 dw16[4];
    #pragma unroll
    for (int kt = 0; kt < 4; kt++) {
        half8 hv;
        #pragma unroll
        for (int e = 0; e < 8; e++)
            hv[e] = (_Float16)dw0[(kt * 32 + quad * 8 + e) * 16 + l15];
        dw16[kt] = hv;
    }
    // pin the weight live-ranges to the AGPR class now (all later uses are
    // "a"-constrained MFMA operands, so they stay resident in a[0:63])
    #pragma unroll
    for (int g = 0; g < 3; g++)
        #pragma unroll
        for (int kt = 0; kt < 4; kt++)
            asm volatile("" : "+a"(wb16[g][kt]));
    #pragma unroll
    for (int kt = 0; kt < 4; kt++)
        asm volatile("" : "+a"(dw16[kt]));

    // gate constants (exp2-prescaled; biases fold into acc init)
    const float wr   = w_ih[jc] * LOG2E;
    const float wz   = w_ih[128 + jc] * LOG2E;
    const float wn   = w_ih[256 + jc] * (2.f * LOG2E);
    const float c_r  = (b_ih[jc] + b_hh[jc]) * LOG2E;
    const float c_z  = (b_ih[128 + jc] + b_hh[128 + jc]) * LOG2E;
    const float c_n  = b_hh[256 + jc] * (2.f * LOG2E);
    const float bnih = b_ih[256 + jc] * (2.f * LOG2E);
    const float db0r = db0[l15];
    const float dw1r = dw1[l15];
    const float db1r = db1[0];

    // precomputed LDS element offsets (plane-relative)
    int rdo[4];
    #pragma unroll
    for (int kt = 0; kt < 4; kt++)
        rdo[kt] = l15 * 128 + (((kt * 4 + quad) + l15) & 15) * 8;
    int wro[4];
    #pragma unroll
    for (int reg = 0; reg < 4; reg++) {
        const int row = quad * 4 + reg;
        wro[reg] = row * 128 + ((((jc >> 3) + row) & 15) << 3) + (jc & 7);
    }
    __syncthreads();

    // ---------------- 50 iterations: dec(h_t) -> out[t]; gates -> h_{t+1} ---
    for (int t = 0; t <= 49; t++) {
        const int cur = t & 1, nxt = cur ^ 1;
        const _Float16* __restrict__ hc = h16 + cur * 2048;
        _Float16* __restrict__ hw = h16 + nxt * 2048;

        // per-kt: one A-frag read feeds 4 AGPR-B MFMAs, then dies
        floatx4 dacc = (floatx4){db0r, db0r, db0r, db0r};
        floatx4 ar = (floatx4){c_r, c_r, c_r, c_r};
        floatx4 az = (floatx4){c_z, c_z, c_z, c_z};
        floatx4 an = (floatx4){c_n, c_n, c_n, c_n};
        #pragma unroll
        for (int kt = 0; kt < 4; kt++) {
            const half8 ahk = *(const half8*)(hc + rdo[kt]);
            mfma_ag(dacc, ahk, dw16[kt]);
            mfma_ag(ar,   ahk, wb16[0][kt]);
            mfma_ag(az,   ahk, wb16[1][kt]);
            mfma_ag(an,   ahk, wb16[2][kt]);
        }

        // serial tail under elevated priority (wins issue arbitration
        // against the other co-resident waves' MFMA/read phases)
        __builtin_amdgcn_s_setprio(1);

        // decoder reduce via DPP (16-lane sum within quad-row, broadcast)
        float xp[4];
        #pragma unroll
        for (int reg = 0; reg < 4; reg++) {
            float v = fmaxf(dacc[reg], 0.f) * dw1r;
            v = dpp_add<0x140>(v);   // row_mirror
            v = dpp_add<0x141>(v);   // row_half_mirror
            v = dpp_add<0x4E>(v);    // quad_perm xor2
            v = dpp_add<0xB1>(v);    // quad_perm xor1
            xp[reg] = (t == 0) ? 0.f : (v + db1r);
        }
        if (t > 0 && w == 0 && l15 == 0) {
            #pragma unroll
            for (int reg = 0; reg < 4; reg++)
                outb[quad * 4 + reg][t] = xp[reg];
        }

        // gates -> h_{t+1}; merged z/n with u = Ey+1 factoring
        if (t < 49) {
            #pragma unroll
            for (int reg = 0; reg < 4; reg++) {
                const float xpv = xp[reg];
                const float hv0 = hold[reg];
                float gr = fmaf(xpv, wr, ar[reg]);
                float gz = fmaf(xpv, wz, az[reg]);
                float Er = __builtin_amdgcn_exp2f(-gr);
                float Ez = __builtin_amdgcn_exp2f(-gz);
                float rg = __builtin_amdgcn_rcpf(1.f + Er);
                float ys = fmaf(rg, an[reg], fmaf(xpv, wn, bnih));
                float Ey = __builtin_amdgcn_exp2f(ys);
                float u   = Ey + 1.f;
                float t1  = fmaf(Ez, Ey, -Ez);       // Ez*(Ey-1)
                float num = fmaf(hv0, u, t1);        // + h*(Ey+1)
                float den = fmaf(Ez, u, u);          // (Ey+1)*(Ez+1)
                const float hn = num * __builtin_amdgcn_rcpf(den);
                hold[reg] = hn;
                hw[wro[reg]] = (_Float16)hn;
            }
        }
        __builtin_amdgcn_s_setprio(0);
        __syncthreads();   // plane[nxt] complete; outb[t] visible
    }

    // coalesced output write: [16 rows][50 cols], col 0 = 0
    for (int e = tid; e < 16 * 50; e += NTH) {
        const int b = e / 50;
        const int tcol = e - b * 50;
        out[(size_t)b0 * 50 + e] = outb[b][tcol];
    }
}

// ---------------------------------------------------------------------------
extern "C" void kernel_launch(void* const* d_in, const int* in_sizes, int n_in,
                              void* d_out, int out_size, void* d_ws, size_t ws_size,
                              hipStream_t stream) {
    const float* x   = (const float*)d_in[0];
    const float* ew0 = (const float*)d_in[1];
    const float* eb0 = (const float*)d_in[2];
    const float* ew1 = (const float*)d_in[3];
    const float* eb1 = (const float*)d_in[4];
    const float* ew2 = (const float*)d_in[5];
    const float* eb2 = (const float*)d_in[6];
    const float* wih = (const float*)d_in[7];
    const float* whh = (const float*)d_in[8];
    const float* bih = (const float*)d_in[9];
    const float* bhh = (const float*)d_in[10];
    const float* dw0 = (const float*)d_in[11];
    const float* db0 = (const float*)d_in[12];
    const float* dw1 = (const float*)d_in[13];
    const float* db1 = (const float*)d_in[14];
    float* out = (float*)d_out;

    gru_fused_kernel<<<512, NTH, 0, stream>>>(
        x, ew0, eb0, ew1, eb1, ew2, eb2, wih, whh, bih, bhh,
        dw0, db0, dw1, db1, out);
}

// Round 10
// 155.829 us; speedup vs baseline: 1.0751x; 1.0751x over previous
//
#include <hip/hip_runtime.h>

#define NTH 256   // 4 waves; 16 rows/block; grid 512 -> 2 blocks/CU (256-reg budget)

typedef _Float16 half8 __attribute__((ext_vector_type(8)));
typedef _Float16 half4 __attribute__((ext_vector_type(4)));
typedef __attribute__((ext_vector_type(4))) float floatx4;
typedef __attribute__((ext_vector_type(2))) float float2v;

#define LOG2E 1.44269504088896340736f

// DPP add stage; 0x140,0x141,0x4E,0xB1 together = 16-lane sum broadcast
template<int CTRL>
__device__ __forceinline__ float dpp_add(float v) {
    int o = __builtin_amdgcn_update_dpp(0, __float_as_int(v), CTRL, 0xF, 0xF, true);
    return v + __int_as_float(o);
}

#define MFMA16 __builtin_amdgcn_mfma_f32_16x16x32_f16

// ---------------------------------------------------------------------------
// Encoder layer core (MFMA): acc[nt] = bias + src[16,K] @ W[K,128] on cols
// jc = w*32 + nt*16 + l15. src is f16 LDS, rows of ROWH halves, 8-elem chunks
// rotation-swizzled by row with mask CMASK. W gathered from global (L2-hot).
// ---------------------------------------------------------------------------
template<int KTILES, int CMASK, int ROWH>
__device__ __forceinline__ void enc_layer(const _Float16* __restrict__ src,
                                          const float* __restrict__ W,
                                          const float* __restrict__ bias,
                                          int w, int quad, int l15,
                                          floatx4 acc[2]) {
    half8 bw[2][KTILES];
    #pragma unroll
    for (int nt = 0; nt < 2; nt++) {
        const int jc = w * 32 + nt * 16 + l15;
        #pragma unroll
        for (int kt = 0; kt < KTILES; kt++) {
            const int kb = kt * 32 + quad * 8;
            half8 hv;
            #pragma unroll
            for (int e = 0; e < 8; e++) hv[e] = (_Float16)W[(kb + e) * 128 + jc];
            bw[nt][kt] = hv;
        }
        const float bv = bias[jc];
        acc[nt] = (floatx4){bv, bv, bv, bv};
    }
    #pragma unroll
    for (int kt = 0; kt < KTILES; kt++) {
        const half8 av = *(const half8*)(src + l15 * ROWH +
                                         (((kt * 4 + quad) + l15) & CMASK) * 8);
        acc[0] = MFMA16(av, bw[0][kt], acc[0], 0, 0, 0);
        acc[1] = MFMA16(av, bw[1][kt], acc[1], 0, 0, 0);
    }
}

// store MFMA C (row=quad*4+reg, col=jc) into f16 [16][128] with &15 swizzle
__device__ __forceinline__ void enc_store(_Float16* __restrict__ dst,
                                          const floatx4 acc[2],
                                          int w, int quad, int l15, bool relu) {
    #pragma unroll
    for (int nt = 0; nt < 2; nt++) {
        const int jc = w * 32 + nt * 16 + l15;
        #pragma unroll
        for (int reg = 0; reg < 4; reg++) {
            const int row = quad * 4 + reg;
            float v = acc[nt][reg];
            if (relu) v = fmaxf(v, 0.f);
            dst[row * 128 + ((((jc >> 3) + row) & 15) << 3) + (jc & 7)] = (_Float16)v;
        }
    }
}

// ---------------------------------------------------------------------------
// R10 = R8 (best, 86.5us) + packed-FP32 gate tail.
// 16 rows/block, 4 waves, 2 blocks/CU at the 256-VGPR budget: zero spill,
// W_hh (96) + dw0 (16) persist. The gate tail is rewritten over float2
// pairs along the reg axis (acc[g][nt] is a floatx4 -> adjacent aligned
// VGPR pairs, zero packing moves) so clang selects v_pk_fma_f32 /
// v_pk_add_f32 / v_pk_mul_f32 (full-rate, 2 elems/inst). Trans ops
// (exp2/rcp) stay scalar (no packed trans). Non-trans gate issue halves;
// measured VALU occupancy is 57% trans / 23% non-trans gate / 20% reduce.
// ---------------------------------------------------------------------------
__global__ __launch_bounds__(NTH, 2)
void gru_fused_kernel(const float* __restrict__ x,
                      const float* __restrict__ ew0, const float* __restrict__ eb0,
                      const float* __restrict__ ew1, const float* __restrict__ eb1,
                      const float* __restrict__ ew2, const float* __restrict__ eb2,
                      const float* __restrict__ w_ih, const float* __restrict__ w_hh,
                      const float* __restrict__ b_ih, const float* __restrict__ b_hh,
                      const float* __restrict__ dw0, const float* __restrict__ db0,
                      const float* __restrict__ dw1, const float* __restrict__ db1,
                      float* __restrict__ out) {
    __shared__ __align__(16) _Float16 encx[16 * 256];   // x stage (8KB); reused as h2
    __shared__ __align__(16) _Float16 h1b[16 * 128];    // layer-1 out (4KB)
    __shared__ __align__(16) _Float16 h16[2 * 16 * 128];// h planes dbuf (8KB)
    __shared__ float outb[16][52];

    const int tid  = threadIdx.x;
    const int b0   = blockIdx.x * 16;
    const int lane = tid & 63;
    const int w    = tid >> 6;     // wave 0..3
    const int quad = lane >> 4;
    const int l15  = lane & 15;

    // ---------------- stage x -> f16 LDS (chunk-rotation swizzle &31) ------
    #pragma unroll
    for (int i = 0; i < 4; i++) {
        const int e = tid + i * NTH;          // 0..1023 float4s
        const int row = e >> 6, c4 = e & 63;
        const float4 xv = *(const float4*)(x + (size_t)(b0 + row) * 256 + c4 * 4);
        half4 hv = {(_Float16)xv.x, (_Float16)xv.y, (_Float16)xv.z, (_Float16)xv.w};
        *(half4*)(encx + row * 256 + (((c4 >> 1) + row) & 31) * 8 + (c4 & 1) * 4) = hv;
    }
    __syncthreads();

    // ---------------- encoder: 3 MFMA layers ----------------
    floatx4 ea[2];
    enc_layer<8, 31, 256>(encx, ew0, eb0, w, quad, l15, ea);
    enc_store(h1b, ea, w, quad, l15, true);
    __syncthreads();
    enc_layer<4, 15, 128>(h1b, ew1, eb1, w, quad, l15, ea);
    enc_store(encx, ea, w, quad, l15, true);       // h2 reuses encx (stride 128)
    __syncthreads();
    enc_layer<4, 15, 128>(encx, ew2, eb2, w, quad, l15, ea);
    // h_0: lane-private fp32 copy (as float2 pairs) + publish f16 plane 0
    float2v hold2[2][2];
    #pragma unroll
    for (int nt = 0; nt < 2; nt++) {
        hold2[nt][0] = (float2v){ea[nt][0], ea[nt][1]};
        hold2[nt][1] = (float2v){ea[nt][2], ea[nt][3]};
    }
    enc_store(h16, ea, w, quad, l15, false);
    if (tid < 16) outb[tid][0] = 0.f;

    // ---------------- persistent register weights (f16, exp2-prescaled) ----
    half8 wb16[3][2][4];
    #pragma unroll
    for (int g = 0; g < 3; g++) {
        const float scale = (g == 2) ? 2.f * LOG2E : LOG2E;
        #pragma unroll
        for (int nt = 0; nt < 2; nt++) {
            const float* wrow = w_hh + (g * 128 + w * 32 + nt * 16 + l15) * 128;
            #pragma unroll
            for (int kt = 0; kt < 4; kt++) {
                const int kb = kt * 32 + quad * 8;
                const float4 w0 = *(const float4*)(wrow + kb);
                const float4 w1 = *(const float4*)(wrow + kb + 4);
                half8 hv;
                hv[0] = (_Float16)(w0.x * scale); hv[1] = (_Float16)(w0.y * scale);
                hv[2] = (_Float16)(w0.z * scale); hv[3] = (_Float16)(w0.w * scale);
                hv[4] = (_Float16)(w1.x * scale); hv[5] = (_Float16)(w1.y * scale);
                hv[6] = (_Float16)(w1.z * scale); hv[7] = (_Float16)(w1.w * scale);
                wb16[g][nt][kt] = hv;
            }
        }
    }
    half8 dw16[4];
    #pragma unroll
    for (int kt = 0; kt < 4; kt++) {
        half8 hv;
        #pragma unroll
        for (int e = 0; e < 8; e++)
            hv[e] = (_Float16)dw0[(kt * 32 + quad * 8 + e) * 16 + l15];
        dw16[kt] = hv;
    }
    // gate constants per nt, duplicated into float2 (pk operands; per-lane)
    float2v wr2[2], wz2[2], wn2[2], bnih2[2];
    float c_r[2], c_z[2], c_n[2];
    #pragma unroll
    for (int nt = 0; nt < 2; nt++) {
        const int jc = w * 32 + nt * 16 + l15;
        const float wr = w_ih[jc] * LOG2E;
        const float wz = w_ih[128 + jc] * LOG2E;
        const float wn = w_ih[256 + jc] * (2.f * LOG2E);
        const float bn = b_ih[256 + jc] * (2.f * LOG2E);
        wr2[nt] = (float2v){wr, wr};
        wz2[nt] = (float2v){wz, wz};
        wn2[nt] = (float2v){wn, wn};
        bnih2[nt] = (float2v){bn, bn};
        c_r[nt] = (b_ih[jc] + b_hh[jc]) * LOG2E;
        c_z[nt] = (b_ih[128 + jc] + b_hh[128 + jc]) * LOG2E;
        c_n[nt] = b_hh[256 + jc] * (2.f * LOG2E);
    }
    const float db0r = db0[l15];
    const float dw1r = dw1[l15];
    const float db1r = db1[0];

    // precomputed LDS element offsets (plane-relative)
    int rdo[4];
    #pragma unroll
    for (int kt = 0; kt < 4; kt++)
        rdo[kt] = l15 * 128 + (((kt * 4 + quad) + l15) & 15) * 8;
    int wro[2][4];
    #pragma unroll
    for (int nt = 0; nt < 2; nt++) {
        const int jc = w * 32 + nt * 16 + l15;
        #pragma unroll
        for (int reg = 0; reg < 4; reg++) {
            const int row = quad * 4 + reg;
            wro[nt][reg] = row * 128 + ((((jc >> 3) + row) & 15) << 3) + (jc & 7);
        }
    }
    __syncthreads();

    // ---------------- 50 iterations: dec(h_t) -> out[t]; gates -> h_{t+1} ---
    for (int t = 0; t <= 49; t++) {
        const int cur = t & 1, nxt = cur ^ 1;
        const _Float16* __restrict__ hc = h16 + cur * 2048;
        _Float16* __restrict__ hw = h16 + nxt * 2048;

        // A-frags (4x ds_read_b128, swizzled, conflict-free)
        half8 ah[4];
        #pragma unroll
        for (int kt = 0; kt < 4; kt++)
            ah[kt] = *(const half8*)(hc + rdo[kt]);

        // decoder: two 2-deep chains (db0 folded into chain-0 init)
        floatx4 dacc0 = (floatx4){db0r, db0r, db0r, db0r};
        floatx4 dacc1 = (floatx4){0.f, 0.f, 0.f, 0.f};
        dacc0 = MFMA16(ah[0], dw16[0], dacc0, 0, 0, 0);
        dacc1 = MFMA16(ah[1], dw16[1], dacc1, 0, 0, 0);
        dacc0 = MFMA16(ah[2], dw16[2], dacc0, 0, 0, 0);
        dacc1 = MFMA16(ah[3], dw16[3], dacc1, 0, 0, 0);

        // GRU MFMAs: biases pre-loaded into accumulators
        floatx4 acc[3][2];
        #pragma unroll
        for (int nt = 0; nt < 2; nt++) {
            acc[0][nt] = (floatx4){c_r[nt], c_r[nt], c_r[nt], c_r[nt]};
            acc[1][nt] = (floatx4){c_z[nt], c_z[nt], c_z[nt], c_z[nt]};
            acc[2][nt] = (floatx4){c_n[nt], c_n[nt], c_n[nt], c_n[nt]};
        }
        #pragma unroll
        for (int kt = 0; kt < 4; kt++)
            #pragma unroll
            for (int g = 0; g < 3; g++) {
                acc[g][0] = MFMA16(ah[kt], wb16[g][0][kt], acc[g][0], 0, 0, 0);
                acc[g][1] = MFMA16(ah[kt], wb16[g][1][kt], acc[g][1], 0, 0, 0);
            }

        // ---- serial tail under elevated priority
        __builtin_amdgcn_s_setprio(1);

        // decoder reduce via DPP (16-lane sum within quad-row, broadcast)
        float xp[4];
        #pragma unroll
        for (int reg = 0; reg < 4; reg++) {
            float v = fmaxf(dacc0[reg] + dacc1[reg], 0.f) * dw1r;
            v = dpp_add<0x140>(v);   // row_mirror
            v = dpp_add<0x141>(v);   // row_half_mirror
            v = dpp_add<0x4E>(v);    // quad_perm xor2
            v = dpp_add<0xB1>(v);    // quad_perm xor1
            xp[reg] = (t == 0) ? 0.f : (v + db1r);
        }
        if (t > 0 && w == 0 && l15 == 0) {
            #pragma unroll
            for (int reg = 0; reg < 4; reg++)
                outb[quad * 4 + reg][t] = xp[reg];
        }

        // gates -> h_{t+1}; merged z/n, packed-f32 pairs over the reg axis
        if (t < 49) {
            const float2v one2 = (float2v){1.f, 1.f};
            #pragma unroll
            for (int nt = 0; nt < 2; nt++)
                #pragma unroll
                for (int p = 0; p < 2; p++) {
                    const float2v xq = (float2v){xp[2 * p], xp[2 * p + 1]};
                    const float2v a_r = (float2v){acc[0][nt][2 * p], acc[0][nt][2 * p + 1]};
                    const float2v a_z = (float2v){acc[1][nt][2 * p], acc[1][nt][2 * p + 1]};
                    const float2v a_n = (float2v){acc[2][nt][2 * p], acc[2][nt][2 * p + 1]};
                    const float2v h0 = hold2[nt][p];
                    float2v gr = __builtin_elementwise_fma(xq, wr2[nt], a_r);
                    float2v gz = __builtin_elementwise_fma(xq, wz2[nt], a_z);
                    float2v Er, Ez, Ey, rg, rd;
                    Er.x = __builtin_amdgcn_exp2f(-gr.x);
                    Er.y = __builtin_amdgcn_exp2f(-gr.y);
                    Ez.x = __builtin_amdgcn_exp2f(-gz.x);
                    Ez.y = __builtin_amdgcn_exp2f(-gz.y);
                    float2v d1 = Er + one2;
                    rg.x = __builtin_amdgcn_rcpf(d1.x);
                    rg.y = __builtin_amdgcn_rcpf(d1.y);
                    float2v ys = __builtin_elementwise_fma(
                        rg, a_n, __builtin_elementwise_fma(xq, wn2[nt], bnih2[nt]));
                    Ey.x = __builtin_amdgcn_exp2f(ys.x);
                    Ey.y = __builtin_amdgcn_exp2f(ys.y);
                    float2v u   = Ey + one2;
                    float2v em1 = Ey - one2;
                    float2v t1  = Ez * em1;                          // Ez*(Ey-1)
                    float2v num = __builtin_elementwise_fma(h0, u, t1);
                    float2v den = __builtin_elementwise_fma(Ez, u, u);
                    rd.x = __builtin_amdgcn_rcpf(den.x);
                    rd.y = __builtin_amdgcn_rcpf(den.y);
                    float2v hn = num * rd;
                    hold2[nt][p] = hn;
                    hw[wro[nt][2 * p]]     = (_Float16)hn.x;
                    hw[wro[nt][2 * p + 1]] = (_Float16)hn.y;
                }
        }
        __builtin_amdgcn_s_setprio(0);
        __syncthreads();   // plane[nxt] complete; outb[t] visible
    }

    // coalesced output write: [16 rows][50 cols], col 0 = 0
    for (int e = tid; e < 16 * 50; e += NTH) {
        const int b = e / 50;
        const int tcol = e - b * 50;
        out[(size_t)b0 * 50 + e] = outb[b][tcol];
    }
}

// ---------------------------------------------------------------------------
extern "C" void kernel_launch(void* const* d_in, const int* in_sizes, int n_in,
                              void* d_out, int out_size, void* d_ws, size_t ws_size,
                              hipStream_t stream) {
    const float* x   = (const float*)d_in[0];
    const float* ew0 = (const float*)d_in[1];
    const float* eb0 = (const float*)d_in[2];
    const float* ew1 = (const float*)d_in[3];
    const float* eb1 = (const float*)d_in[4];
    const float* ew2 = (const float*)d_in[5];
    const float* eb2 = (const float*)d_in[6];
    const float* wih = (const float*)d_in[7];
    const float* whh = (const float*)d_in[8];
    const float* bih = (const float*)d_in[9];
    const float* bhh = (const float*)d_in[10];
    const float* dw0 = (const float*)d_in[11];
    const float* db0 = (const float*)d_in[12];
    const float* dw1 = (const float*)d_in[13];
    const float* db1 = (const float*)d_in[14];
    float* out = (float*)d_out;

    gru_fused_kernel<<<512, NTH, 0, stream>>>(
        x, ew0, eb0, ew1, eb1, ew2, eb2, wih, whh, bih, bhh,
        dw0, db0, dw1, db1, out);
}